// Round 17
// baseline (687.378 us; speedup 1.0000x reference)
//
#include <hip/hip_runtime.h>

typedef unsigned long long u64;

constexpr int TPB = 256;
constexpr int BM = 64, BN = 64, BK = 16;
constexpr int T  = 50;
constexpr int M  = 512;   // batch

// Fused: C = A @ W^T + b (f32), then f32 LIF (V = fadd(fmul(V,0.9f),I);
// spike V > 1.0f; reset 0), then coalesced f32 spike writes.
// Reference semantics (r16-certified): KC=512 unbalanced K-blocks
// (1024 -> 512+512; 2048 -> 512x4), ONE sequential k-ascending FMA chain
// per C element per block, blocks merged into C with rounded f32 adds
// (exact on first), bias added after; LIF mul/add uncontracted;
// mean = fdiv(count, 50).
// IN_COUNT: A holds integer spike counts; value = f32_div(count, 50)
template<bool IN_COUNT, bool WRITE_CNT>
__global__ __launch_bounds__(TPB)
void lif_gemm(const float* __restrict__ A, const int K, const int N,
              const float* __restrict__ W, const float* __restrict__ bias,
              float* __restrict__ outS, float* __restrict__ cntOut)
{
    __shared__ float sA[BM][BK + 1];
    __shared__ float sB[BN][BK + 1];
    __shared__ u64   smask[BM][BN];

    const int tid = threadIdx.x;
    const int tx  = tid & 15;
    const int ty  = tid >> 4;
    const int n0  = blockIdx.x * BN;
    const int m0  = blockIdx.y * BM;

    const int lr = tid >> 2;
    const int lc = (tid & 3) << 2;

    float S[4][4];     // current kc-block partial (single FMA chain)
    float Ia[4][4];    // merged C across kc blocks
    #pragma unroll
    for (int i = 0; i < 4; ++i)
        #pragma unroll
        for (int j = 0; j < 4; ++j) { S[i][j] = 0.0f; Ia[i][j] = 0.0f; }

    const float* aptr = A + (size_t)(m0 + lr) * K + lc;
    const float* wptr = W + (size_t)(n0 + lr) * K + lc;

    for (int k0 = 0; k0 < K; k0 += BK) {
        float4 va = *reinterpret_cast<const float4*>(aptr + k0);
        float4 vw = *reinterpret_cast<const float4*>(wptr + k0);
        if constexpr (IN_COUNT) {
            sA[lr][lc + 0] = __fdiv_rn(va.x, 50.0f);
            sA[lr][lc + 1] = __fdiv_rn(va.y, 50.0f);
            sA[lr][lc + 2] = __fdiv_rn(va.z, 50.0f);
            sA[lr][lc + 3] = __fdiv_rn(va.w, 50.0f);
        } else {
            sA[lr][lc + 0] = va.x;
            sA[lr][lc + 1] = va.y;
            sA[lr][lc + 2] = va.z;
            sA[lr][lc + 3] = va.w;
        }
        sB[lr][lc + 0] = vw.x;
        sB[lr][lc + 1] = vw.y;
        sB[lr][lc + 2] = vw.z;
        sB[lr][lc + 3] = vw.w;
        __syncthreads();

        #pragma unroll
        for (int kk = 0; kk < BK; ++kk) {
            float a[4], b[4];
            #pragma unroll
            for (int i = 0; i < 4; ++i) a[i] = sA[ty * 4 + i][kk];
            #pragma unroll
            for (int j = 0; j < 4; ++j) b[j] = sB[tx * 4 + j][kk];
            #pragma unroll
            for (int i = 0; i < 4; ++i)
                #pragma unroll
                for (int j = 0; j < 4; ++j)
                    S[i][j] = __fmaf_rn(a[i], b[j], S[i][j]);
        }
        __syncthreads();

        // KC=512 block boundary: merge register partial into C
        if (((k0 + BK) & 511) == 0) {
            #pragma unroll
            for (int i = 0; i < 4; ++i)
                #pragma unroll
                for (int j = 0; j < 4; ++j) {
                    Ia[i][j] = __fadd_rn(Ia[i][j], S[i][j]);  // exact on first
                    S[i][j]  = 0.0f;
                }
        }
    }

    // f32 LIF dynamics (numpy elementwise: mul rounded, add rounded)
    #pragma unroll
    for (int i = 0; i < 4; ++i) {
        #pragma unroll
        for (int j = 0; j < 4; ++j) {
            const int mi = ty * 4 + i;
            const int nj = tx * 4 + j;
            const float I = __fadd_rn(Ia[i][j], bias[n0 + nj]);
            float V = 0.0f;
            u64 msk = 0ull;
            #pragma unroll 1
            for (int t = 0; t < T; ++t) {
                V = __fadd_rn(__fmul_rn(V, 0.9f), I);
                if (V > 1.0f) { V = 0.0f; msk |= (1ull << t); }
            }
            smask[mi][nj] = msk;
            if constexpr (WRITE_CNT) {
                cntOut[(size_t)(m0 + mi) * N + (n0 + nj)] = (float)__popcll(msk);
            }
        }
    }
    __syncthreads();

    // Coalesced spike write: block region = BM rows x (BN*T) floats
    constexpr int ROWLEN = BN * T;            // 3200
    constexpr int TOTQ   = BM * ROWLEN / 4;   // 51200 float4s
    for (int idx = tid; idx < TOTQ; idx += TPB) {
        const int q   = idx << 2;
        const int row = q / ROWLEN;
        const int rem = q - row * ROWLEN;
        int nn = rem / T;
        int tt = rem - nn * T;
        u64 msk = smask[row][nn];
        float vals[4];
        #pragma unroll
        for (int c = 0; c < 4; ++c) {
            if (tt >= T) { tt -= T; ++nn; msk = smask[row][nn]; }
            vals[c] = (float)((msk >> tt) & 1ull);
            ++tt;
        }
        float4 v4 = make_float4(vals[0], vals[1], vals[2], vals[3]);
        const size_t off = ((size_t)(m0 + row) * N + n0) * T + rem;
        *reinterpret_cast<float4*>(outS + off) = v4;
    }
}

__global__ __launch_bounds__(TPB)
void copy_f4(const float* __restrict__ src, float* __restrict__ dst, int nquads)
{
    int i = blockIdx.x * blockDim.x + threadIdx.x;
    int stride = gridDim.x * blockDim.x;
    for (; i < nquads; i += stride) {
        reinterpret_cast<float4*>(dst)[i] =
            reinterpret_cast<const float4*>(src)[i];
    }
}

extern "C" void kernel_launch(void* const* d_in, const int* in_sizes, int n_in,
                              void* d_out, int out_size, void* d_ws, size_t ws_size,
                              hipStream_t stream) {
    const float* x  = (const float*)d_in[0];
    const float* W0 = (const float*)d_in[1];
    const float* b0 = (const float*)d_in[2];
    const float* W1 = (const float*)d_in[3];
    const float* b1 = (const float*)d_in[4];
    const float* W2 = (const float*)d_in[5];
    const float* b2 = (const float*)d_in[6];
    float* out = (float*)d_out;

    constexpr int H = 2048, DOUT = 1024;
    const size_t s2sz = (size_t)M * DOUT * T;
    const size_t s0sz = (size_t)M * H * T;

    // d_out layout (return order, f32 — r13-proven): [s2a | s0 | s1 | s2b]
    float* s2a = out;
    float* s0  = out + s2sz;
    float* s1  = s0 + s0sz;
    float* s2b = s1 + s0sz;

    // inter-layer count stash inside d_out (race-free by schedule):
    //   cnt0 -> s2b region (dead before L2 overwrites s2b)
    //   cnt1 -> s2a region (dead before final copy rewrites s2a)
    float* cnt0 = s2b;
    float* cnt1 = s2a;

    dim3 blk(TPB);
    dim3 gH(H / BN, M / BM), gD(DOUT / BN, M / BM);

    // layer 0: x[512,1024] @ W0^T -> [512,2048]
    lif_gemm<false, true><<<gH, blk, 0, stream>>>(x, 1024, H, W0, b0, s0, cnt0);
    // layer 1: (cnt0/50)[512,2048] @ W1^T -> [512,2048]
    lif_gemm<true, true><<<gH, blk, 0, stream>>>(cnt0, H, H, W1, b1, s1, cnt1);
    // layer 2: (cnt1/50)[512,2048] @ W2^T -> [512,1024], writes s2b only
    lif_gemm<true, false><<<gD, blk, 0, stream>>>(cnt1, H, DOUT, W2, b2, s2b, nullptr);
    // replicate: s2a <- s2b (also overwrites the cnt1 stash)
    copy_f4<<<2048, blk, 0, stream>>>(s2b, s2a, (int)(s2sz / 4));
}

// Round 18
// 484.060 us; speedup vs baseline: 1.4200x; 1.4200x over previous
//
#include <hip/hip_runtime.h>

typedef unsigned long long u64;

constexpr int TPB = 256;
constexpr int BM = 64, BN = 64, BK = 64;
constexpr int T  = 50;
constexpr int M  = 512;   // batch

// Fused: C = A @ W^T + b (f32), then f32 LIF (V = fadd(fmul(V,0.9f),I);
// spike V > 1.0f; reset 0), then coalesced f32 spike writes.
// Reference semantics (r16-certified, bit-exact r17): KC=512 unbalanced
// K-blocks, ONE sequential k-ascending FMA chain per C element per block,
// blocks merged into C with rounded f32 adds (exact on first), bias after;
// LIF mul/add uncontracted; mean = fdiv(count, 50).
// k-major LDS tiles -> ds_read_b128 fragment loads (r17 was scalar-bound).
template<bool IN_COUNT, bool WRITE_CNT, bool DUP>
__global__ __launch_bounds__(TPB)
void lif_gemm(const float* __restrict__ A, const int K, const int N,
              const float* __restrict__ W, const float* __restrict__ bias,
              float* __restrict__ outS, float* __restrict__ outDup,
              float* __restrict__ cntOut)
{
    __shared__ float sA[BK][BM + 4];   // k-major: row stride 68 floats (272B)
    __shared__ float sB[BK][BN + 4];
    __shared__ u64   smask[BM][BN];

    const int tid = threadIdx.x;
    const int tx  = tid & 15;
    const int ty  = tid >> 4;
    const int n0  = blockIdx.x * BN;
    const int m0  = blockIdx.y * BM;

    const int lr = tid >> 2;         // 0..63: tile row this thread stages
    const int lc = (tid & 3) << 2;   // 0,4,8,12: base k within 16-chunk

    float S[4][4];     // current kc-block partial (single FMA chain)
    float Ia[4][4];    // merged C across kc blocks
    #pragma unroll
    for (int i = 0; i < 4; ++i)
        #pragma unroll
        for (int j = 0; j < 4; ++j) { S[i][j] = 0.0f; Ia[i][j] = 0.0f; }

    const float* aptr = A + (size_t)(m0 + lr) * K;
    const float* wptr = W + (size_t)(n0 + lr) * K;

    for (int k0 = 0; k0 < K; k0 += BK) {
        // stage: each thread loads 4 float4s of A-row and W-row (16 k each)
        float4 va[4], vw[4];
        #pragma unroll
        for (int c = 0; c < 4; ++c) {
            va[c] = *reinterpret_cast<const float4*>(aptr + k0 + lc + 16 * c);
            vw[c] = *reinterpret_cast<const float4*>(wptr + k0 + lc + 16 * c);
        }
        __syncthreads();   // previous compute done before LDS overwrite
        #pragma unroll
        for (int c = 0; c < 4; ++c) {
            const int kb = lc + 16 * c;
            if constexpr (IN_COUNT) {
                sA[kb + 0][lr] = __fdiv_rn(va[c].x, 50.0f);
                sA[kb + 1][lr] = __fdiv_rn(va[c].y, 50.0f);
                sA[kb + 2][lr] = __fdiv_rn(va[c].z, 50.0f);
                sA[kb + 3][lr] = __fdiv_rn(va[c].w, 50.0f);
            } else {
                sA[kb + 0][lr] = va[c].x;
                sA[kb + 1][lr] = va[c].y;
                sA[kb + 2][lr] = va[c].z;
                sA[kb + 3][lr] = va[c].w;
            }
            sB[kb + 0][lr] = vw[c].x;
            sB[kb + 1][lr] = vw[c].y;
            sB[kb + 2][lr] = vw[c].z;
            sB[kb + 3][lr] = vw[c].w;
        }
        __syncthreads();

        #pragma unroll
        for (int kk = 0; kk < BK; ++kk) {
            const float4 a4 = *reinterpret_cast<const float4*>(&sA[kk][ty * 4]);
            const float4 b4 = *reinterpret_cast<const float4*>(&sB[kk][tx * 4]);
            const float a[4] = {a4.x, a4.y, a4.z, a4.w};
            const float b[4] = {b4.x, b4.y, b4.z, b4.w};
            #pragma unroll
            for (int i = 0; i < 4; ++i)
                #pragma unroll
                for (int j = 0; j < 4; ++j)
                    S[i][j] = __fmaf_rn(a[i], b[j], S[i][j]);
        }

        // KC=512 block boundary: merge register partial into C
        if (((k0 + BK) & 511) == 0) {
            #pragma unroll
            for (int i = 0; i < 4; ++i)
                #pragma unroll
                for (int j = 0; j < 4; ++j) {
                    Ia[i][j] = __fadd_rn(Ia[i][j], S[i][j]);  // exact on first
                    S[i][j]  = 0.0f;
                }
        }
    }

    // f32 LIF dynamics (numpy elementwise: mul rounded, add rounded)
    #pragma unroll
    for (int i = 0; i < 4; ++i) {
        #pragma unroll
        for (int j = 0; j < 4; ++j) {
            const int mi = ty * 4 + i;
            const int nj = tx * 4 + j;
            const float I = __fadd_rn(Ia[i][j], bias[n0 + nj]);
            float V = 0.0f;
            u64 msk = 0ull;
            #pragma unroll 1
            for (int t = 0; t < T; ++t) {
                V = __fadd_rn(__fmul_rn(V, 0.9f), I);
                if (V > 1.0f) { V = 0.0f; msk |= (1ull << t); }
            }
            smask[mi][nj] = msk;
            if constexpr (WRITE_CNT) {
                cntOut[(size_t)(m0 + mi) * N + (n0 + nj)] = (float)__popcll(msk);
            }
        }
    }
    __syncthreads();

    // Coalesced spike write: block region = BM rows x (BN*T) floats
    constexpr int ROWLEN = BN * T;            // 3200
    constexpr int TOTQ   = BM * ROWLEN / 4;   // 51200 float4s
    for (int idx = tid; idx < TOTQ; idx += TPB) {
        const int q   = idx << 2;
        const int row = q / ROWLEN;
        const int rem = q - row * ROWLEN;
        int nn = rem / T;
        int tt = rem - nn * T;
        u64 msk = smask[row][nn];
        float vals[4];
        #pragma unroll
        for (int c = 0; c < 4; ++c) {
            if (tt >= T) { tt -= T; ++nn; msk = smask[row][nn]; }
            vals[c] = (float)((msk >> tt) & 1ull);
            ++tt;
        }
        float4 v4 = make_float4(vals[0], vals[1], vals[2], vals[3]);
        const size_t off = ((size_t)(m0 + row) * N + n0) * T + rem;
        *reinterpret_cast<float4*>(outS + off) = v4;
        if constexpr (DUP) *reinterpret_cast<float4*>(outDup + off) = v4;
    }
}

__global__ __launch_bounds__(TPB)
void copy_f4(const float* __restrict__ src, float* __restrict__ dst, int nquads)
{
    int i = blockIdx.x * blockDim.x + threadIdx.x;
    int stride = gridDim.x * blockDim.x;
    for (; i < nquads; i += stride) {
        reinterpret_cast<float4*>(dst)[i] =
            reinterpret_cast<const float4*>(src)[i];
    }
}

extern "C" void kernel_launch(void* const* d_in, const int* in_sizes, int n_in,
                              void* d_out, int out_size, void* d_ws, size_t ws_size,
                              hipStream_t stream) {
    const float* x  = (const float*)d_in[0];
    const float* W0 = (const float*)d_in[1];
    const float* b0 = (const float*)d_in[2];
    const float* W1 = (const float*)d_in[3];
    const float* b1 = (const float*)d_in[4];
    const float* W2 = (const float*)d_in[5];
    const float* b2 = (const float*)d_in[6];
    float* out = (float*)d_out;

    constexpr int H = 2048, DOUT = 1024;
    const size_t s2sz = (size_t)M * DOUT * T;
    const size_t s0sz = (size_t)M * H * T;
    const size_t cntsz = (size_t)M * H;         // 1,048,576 floats

    // d_out layout (return order, f32): [s2a | s0 | s1 | s2b]
    float* s2a = out;
    float* s0  = out + s2sz;
    float* s1  = s0 + s0sz;
    float* s2b = s1 + s0sz;

    dim3 blk(TPB);
    dim3 gH(H / BN, M / BM), gD(DOUT / BN, M / BM);

    if (ws_size >= 2 * cntsz * sizeof(float)) {
        // counts in d_ws; L2 dup-writes both s2 regions (no copy kernel)
        float* cnt0 = (float*)d_ws;
        float* cnt1 = cnt0 + cntsz;
        lif_gemm<false, true, false><<<gH, blk, 0, stream>>>(
            x, 1024, H, W0, b0, s0, nullptr, cnt0);
        lif_gemm<true, true, false><<<gH, blk, 0, stream>>>(
            cnt0, H, H, W1, b1, s1, nullptr, cnt1);
        lif_gemm<true, false, true><<<gD, blk, 0, stream>>>(
            cnt1, H, DOUT, W2, b2, s2b, s2a, nullptr);
    } else {
        // fallback: stash counts inside d_out (r17-proven schedule) + copy
        float* cnt0 = s2b;
        float* cnt1 = s2a;
        lif_gemm<false, true, false><<<gH, blk, 0, stream>>>(
            x, 1024, H, W0, b0, s0, nullptr, cnt0);
        lif_gemm<true, true, false><<<gH, blk, 0, stream>>>(
            cnt0, H, H, W1, b1, s1, nullptr, cnt1);
        lif_gemm<true, false, false><<<gD, blk, 0, stream>>>(
            cnt1, H, DOUT, W2, b2, s2b, nullptr, nullptr);
        copy_f4<<<2048, blk, 0, stream>>>(s2b, s2a, (int)(s2sz / 4));
    }
}

// Round 19
// 448.716 us; speedup vs baseline: 1.5319x; 1.0788x over previous
//
#include <hip/hip_runtime.h>

typedef unsigned long long u64;
typedef unsigned int u32;

constexpr int TPB = 256;
constexpr int BM = 64, BN = 64, BK = 64;
constexpr int T  = 50;
constexpr int M  = 512;   // batch

// ---------------------------------------------------------------------------
// A-kernel: C = A @ W^T + b (r16-certified order: KC=512 unbalanced blocks,
// one sequential k-ascending FMA chain per element per block, f32 block
// merges, bias after), f32 LIF (mul/add uncontracted), output = u64 spike
// mask per neuron. IN_MASK: input A is a u64 mask array; value =
// fdiv(popcount, 50) — bit-identical to the previous cnt/50 path.
// Register-prefetch pipeline: tile t+1's global loads issued before compute.
// ---------------------------------------------------------------------------
template<bool IN_MASK>
__global__ __launch_bounds__(TPB)
void lif_gemm_mask(const void* __restrict__ Ain, const int K, const int N,
                   const float* __restrict__ W, const float* __restrict__ bias,
                   u64* __restrict__ maskOut)
{
    __shared__ float sA[BK][BM + 4];
    __shared__ float sB[BK][BN + 4];

    const int tid = threadIdx.x;
    const int tx  = tid & 15;
    const int ty  = tid >> 4;
    const int n0  = blockIdx.x * BN;
    const int m0  = blockIdx.y * BM;

    const int lr  = tid >> 2;          // staged row
    const int klc = (tid & 3) << 4;    // k-base: 16 consecutive k per thread

    float S[4][4], Ia[4][4];
    #pragma unroll
    for (int i = 0; i < 4; ++i)
        #pragma unroll
        for (int j = 0; j < 4; ++j) { S[i][j] = 0.0f; Ia[i][j] = 0.0f; }

    const float* aF = (const float*)Ain + (size_t)(m0 + lr) * K + klc;
    const u64*   aM = (const u64*)Ain   + (size_t)(m0 + lr) * K + klc;
    const float* wp = W + (size_t)(n0 + lr) * K + klc;

    float4 fa[4];   // A staging (float input)
    uint4  ma[8];   // A staging (mask input): 16 u64
    float4 fw[4];   // W staging

    auto loadA = [&](int k0) {
        if constexpr (IN_MASK) {
            const uint4* p = reinterpret_cast<const uint4*>(aM + k0);
            #pragma unroll
            for (int c = 0; c < 8; ++c) ma[c] = p[c];
        } else {
            #pragma unroll
            for (int c = 0; c < 4; ++c)
                fa[c] = *reinterpret_cast<const float4*>(aF + k0 + 4 * c);
        }
    };
    auto loadW = [&](int k0) {
        #pragma unroll
        for (int c = 0; c < 4; ++c)
            fw[c] = *reinterpret_cast<const float4*>(wp + k0 + 4 * c);
    };

    const int NT = K / BK;
    loadA(0); loadW(0);

    for (int t = 0; t < NT; ++t) {
        __syncthreads();   // previous compute done: LDS free
        if constexpr (IN_MASK) {
            #pragma unroll
            for (int i = 0; i < 16; ++i) {
                const u32 lo = (i & 1) ? ma[i >> 1].z : ma[i >> 1].x;
                const u32 hi = (i & 1) ? ma[i >> 1].w : ma[i >> 1].y;
                const int pc = __popc(lo) + __popc(hi);
                sA[klc + i][lr] = __fdiv_rn((float)pc, 50.0f);
            }
        } else {
            #pragma unroll
            for (int c = 0; c < 4; ++c) {
                sA[klc + 4 * c + 0][lr] = fa[c].x;
                sA[klc + 4 * c + 1][lr] = fa[c].y;
                sA[klc + 4 * c + 2][lr] = fa[c].z;
                sA[klc + 4 * c + 3][lr] = fa[c].w;
            }
        }
        #pragma unroll
        for (int c = 0; c < 4; ++c) {
            sB[klc + 4 * c + 0][lr] = fw[c].x;
            sB[klc + 4 * c + 1][lr] = fw[c].y;
            sB[klc + 4 * c + 2][lr] = fw[c].z;
            sB[klc + 4 * c + 3][lr] = fw[c].w;
        }
        __syncthreads();

        if (t + 1 < NT) { loadA((t + 1) * BK); loadW((t + 1) * BK); }

        #pragma unroll
        for (int kk = 0; kk < BK; ++kk) {
            const float4 a4 = *reinterpret_cast<const float4*>(&sA[kk][ty * 4]);
            const float4 b4 = *reinterpret_cast<const float4*>(&sB[kk][tx * 4]);
            const float a[4] = {a4.x, a4.y, a4.z, a4.w};
            const float b[4] = {b4.x, b4.y, b4.z, b4.w};
            #pragma unroll
            for (int i = 0; i < 4; ++i)
                #pragma unroll
                for (int j = 0; j < 4; ++j)
                    S[i][j] = __fmaf_rn(a[i], b[j], S[i][j]);
        }

        if ((((t + 1) * BK) & 511) == 0) {   // KC=512 boundary
            #pragma unroll
            for (int i = 0; i < 4; ++i)
                #pragma unroll
                for (int j = 0; j < 4; ++j) {
                    Ia[i][j] = __fadd_rn(Ia[i][j], S[i][j]);  // exact on first
                    S[i][j]  = 0.0f;
                }
        }
    }

    // f32 LIF -> u64 masks
    #pragma unroll
    for (int i = 0; i < 4; ++i) {
        #pragma unroll
        for (int j = 0; j < 4; ++j) {
            const int mi = ty * 4 + i;
            const int nj = tx * 4 + j;
            const float I = __fadd_rn(Ia[i][j], bias[n0 + nj]);
            float V = 0.0f;
            u64 msk = 0ull;
            #pragma unroll 1
            for (int t = 0; t < T; ++t) {
                V = __fadd_rn(__fmul_rn(V, 0.9f), I);
                if (V > 1.0f) { V = 0.0f; msk |= (1ull << t); }
            }
            maskOut[(size_t)(m0 + mi) * N + (n0 + nj)] = msk;
        }
    }
}

// ---------------------------------------------------------------------------
// B-kernel: mask -> spike-train expansion. One block = 256 consecutive
// neurons = 12800 contiguous floats; pure streaming float4 writes.
// ---------------------------------------------------------------------------
template<bool DUP>
__global__ __launch_bounds__(TPB)
void expand_spikes(const u64* __restrict__ mask, float* __restrict__ out,
                   float* __restrict__ dup)
{
    __shared__ u64 lm[TPB];
    const int tid = threadIdx.x;
    const size_t base = (size_t)blockIdx.x * TPB;
    lm[tid] = mask[base + tid];
    __syncthreads();

    constexpr int TOTQ = TPB * T / 4;   // 3200 float4s
    for (int idx = tid; idx < TOTQ; idx += TPB) {
        const int q = idx << 2;
        int nn = q / T;
        int tt = q - nn * T;
        u64 mk = lm[nn];
        float vals[4];
        #pragma unroll
        for (int c = 0; c < 4; ++c) {
            if (tt >= T) { tt -= T; ++nn; mk = lm[nn]; }
            vals[c] = (float)((mk >> tt) & 1ull);
            ++tt;
        }
        const float4 v4 = make_float4(vals[0], vals[1], vals[2], vals[3]);
        const size_t off = base * T + q;
        *reinterpret_cast<float4*>(out + off) = v4;
        if constexpr (DUP) *reinterpret_cast<float4*>(dup + off) = v4;
    }
}

// ---------------------------------------------------------------------------
// Fallback A2 (r18-proven fused path, mask input, writes spikes directly)
// ---------------------------------------------------------------------------
__global__ __launch_bounds__(TPB)
void lif_gemm_full(const u64* __restrict__ Ain, const int K, const int N,
                   const float* __restrict__ W, const float* __restrict__ bias,
                   float* __restrict__ outS)
{
    __shared__ float sA[BK][BM + 4];
    __shared__ float sB[BK][BN + 4];
    __shared__ u64   smask[BM][BN];

    const int tid = threadIdx.x;
    const int tx  = tid & 15;
    const int ty  = tid >> 4;
    const int n0  = blockIdx.x * BN;
    const int m0  = blockIdx.y * BM;
    const int lr  = tid >> 2;
    const int klc = (tid & 3) << 4;

    float S[4][4], Ia[4][4];
    #pragma unroll
    for (int i = 0; i < 4; ++i)
        #pragma unroll
        for (int j = 0; j < 4; ++j) { S[i][j] = 0.0f; Ia[i][j] = 0.0f; }

    const u64*   aM = Ain + (size_t)(m0 + lr) * K + klc;
    const float* wp = W + (size_t)(n0 + lr) * K + klc;

    for (int k0 = 0; k0 < K; k0 += BK) {
        uint4 ma[8]; float4 fw[4];
        const uint4* p = reinterpret_cast<const uint4*>(aM + k0);
        #pragma unroll
        for (int c = 0; c < 8; ++c) ma[c] = p[c];
        #pragma unroll
        for (int c = 0; c < 4; ++c)
            fw[c] = *reinterpret_cast<const float4*>(wp + k0 + 4 * c);
        __syncthreads();
        #pragma unroll
        for (int i = 0; i < 16; ++i) {
            const u32 lo = (i & 1) ? ma[i >> 1].z : ma[i >> 1].x;
            const u32 hi = (i & 1) ? ma[i >> 1].w : ma[i >> 1].y;
            sA[klc + i][lr] = __fdiv_rn((float)(__popc(lo) + __popc(hi)), 50.0f);
        }
        #pragma unroll
        for (int c = 0; c < 4; ++c) {
            sB[klc + 4 * c + 0][lr] = fw[c].x;
            sB[klc + 4 * c + 1][lr] = fw[c].y;
            sB[klc + 4 * c + 2][lr] = fw[c].z;
            sB[klc + 4 * c + 3][lr] = fw[c].w;
        }
        __syncthreads();
        #pragma unroll
        for (int kk = 0; kk < BK; ++kk) {
            const float4 a4 = *reinterpret_cast<const float4*>(&sA[kk][ty * 4]);
            const float4 b4 = *reinterpret_cast<const float4*>(&sB[kk][tx * 4]);
            const float a[4] = {a4.x, a4.y, a4.z, a4.w};
            const float b[4] = {b4.x, b4.y, b4.z, b4.w};
            #pragma unroll
            for (int i = 0; i < 4; ++i)
                #pragma unroll
                for (int j = 0; j < 4; ++j)
                    S[i][j] = __fmaf_rn(a[i], b[j], S[i][j]);
        }
        if (((k0 + BK) & 511) == 0) {
            #pragma unroll
            for (int i = 0; i < 4; ++i)
                #pragma unroll
                for (int j = 0; j < 4; ++j) {
                    Ia[i][j] = __fadd_rn(Ia[i][j], S[i][j]);
                    S[i][j]  = 0.0f;
                }
        }
    }

    #pragma unroll
    for (int i = 0; i < 4; ++i)
        #pragma unroll
        for (int j = 0; j < 4; ++j) {
            const int mi = ty * 4 + i, nj = tx * 4 + j;
            const float I = __fadd_rn(Ia[i][j], bias[n0 + nj]);
            float V = 0.0f; u64 msk = 0ull;
            #pragma unroll 1
            for (int t = 0; t < T; ++t) {
                V = __fadd_rn(__fmul_rn(V, 0.9f), I);
                if (V > 1.0f) { V = 0.0f; msk |= (1ull << t); }
            }
            smask[mi][nj] = msk;
        }
    __syncthreads();

    constexpr int ROWLEN = BN * T;
    constexpr int TOTQ   = BM * ROWLEN / 4;
    for (int idx = tid; idx < TOTQ; idx += TPB) {
        const int q = idx << 2;
        const int row = q / ROWLEN;
        const int rem = q - row * ROWLEN;
        int nn = rem / T, tt = rem - nn * T;
        u64 mk = smask[row][nn];
        float vals[4];
        #pragma unroll
        for (int c = 0; c < 4; ++c) {
            if (tt >= T) { tt -= T; ++nn; mk = smask[row][nn]; }
            vals[c] = (float)((mk >> tt) & 1ull);
            ++tt;
        }
        const float4 v4 = make_float4(vals[0], vals[1], vals[2], vals[3]);
        *reinterpret_cast<float4*>(outS + ((size_t)(m0 + row) * N + n0) * T + rem) = v4;
    }
}

__global__ __launch_bounds__(TPB)
void copy_f4(const float* __restrict__ src, float* __restrict__ dst, int nquads)
{
    int i = blockIdx.x * blockDim.x + threadIdx.x;
    int stride = gridDim.x * blockDim.x;
    for (; i < nquads; i += stride)
        reinterpret_cast<float4*>(dst)[i] = reinterpret_cast<const float4*>(src)[i];
}

extern "C" void kernel_launch(void* const* d_in, const int* in_sizes, int n_in,
                              void* d_out, int out_size, void* d_ws, size_t ws_size,
                              hipStream_t stream) {
    const float* x  = (const float*)d_in[0];
    const float* W0 = (const float*)d_in[1];
    const float* b0 = (const float*)d_in[2];
    const float* W1 = (const float*)d_in[3];
    const float* b1 = (const float*)d_in[4];
    const float* W2 = (const float*)d_in[5];
    const float* b2 = (const float*)d_in[6];
    float* out = (float*)d_out;

    constexpr int H = 2048, DOUT = 1024;
    const size_t s2sz = (size_t)M * DOUT * T;
    const size_t s0sz = (size_t)M * H * T;

    // d_out layout (f32, r13/r17-proven): [s2a | s0 | s1 | s2b]
    float* s2a = out;
    float* s0  = out + s2sz;
    float* s1  = s0 + s0sz;
    float* s2b = s1 + s0sz;

    // mask stashes (race-free by schedule):
    //   mask0 @ s1 head  (killed by B1; consumers A1, B0 run first)
    //   mask1 @ s2a head (killed by B2; consumers A2, B1 run first)
    //   mask2 @ d_ws     (4.2 MB)
    u64* mask0 = (u64*)s1;
    u64* mask1 = (u64*)s2a;
    u64* mask2 = (u64*)d_ws;

    dim3 blk(TPB);
    dim3 gH(H / BN, M / BM), gD(DOUT / BN, M / BM);

    if (ws_size >= (size_t)M * DOUT * sizeof(u64)) {
        lif_gemm_mask<false><<<gH, blk, 0, stream>>>(x, 1024, H, W0, b0, mask0);
        lif_gemm_mask<true ><<<gH, blk, 0, stream>>>(mask0, H, H, W1, b1, mask1);
        lif_gemm_mask<true ><<<gD, blk, 0, stream>>>(mask1, H, DOUT, W2, b2, mask2);
        expand_spikes<false><<<(int)(M * H / TPB), blk, 0, stream>>>(mask0, s0, nullptr);
        expand_spikes<false><<<(int)(M * H / TPB), blk, 0, stream>>>(mask1, s1, nullptr);
        expand_spikes<true ><<<(int)(M * DOUT / TPB), blk, 0, stream>>>(mask2, s2b, s2a);
    } else {
        // fallback: no ws. A2 = fused r18-style kernel writing s2b; then copy.
        lif_gemm_mask<false><<<gH, blk, 0, stream>>>(x, 1024, H, W0, b0, mask0);
        lif_gemm_mask<true ><<<gH, blk, 0, stream>>>(mask0, H, H, W1, b1, mask1);
        expand_spikes<false><<<(int)(M * H / TPB), blk, 0, stream>>>(mask0, s0, nullptr);
        expand_spikes<false><<<(int)(M * H / TPB), blk, 0, stream>>>(mask1, s1, nullptr);
        lif_gemm_full<<<gD, blk, 0, stream>>>(mask1, H, DOUT, W2, b2, s2b);
        copy_f4<<<2048, blk, 0, stream>>>(s2b, s2a, (int)(s2sz / 4));
    }
}

// Round 20
// 298.389 us; speedup vs baseline: 2.3036x; 1.5038x over previous
//
#include <hip/hip_runtime.h>

typedef unsigned long long u64;
typedef unsigned int u32;

constexpr int TPB = 256;
constexpr int BM = 64, BN = 64, BK = 64;
constexpr int T  = 50;
constexpr int M  = 512;   // batch

// ---------------------------------------------------------------------------
// A-kernel (split-K): computes ONE KC=512 chain partial of C = A @ W^T.
// blockIdx.z = chain index; chain c covers k in [512c, 512c+512), summed as
// one sequential k-ascending FMA chain (r16-certified micro-order).
// IN_MASK: A is u64 spike-mask array; value = fdiv(popcount, 50).
// ---------------------------------------------------------------------------
template<bool IN_MASK>
__global__ __launch_bounds__(TPB)
void gemm_part(const void* __restrict__ Ain, const int K, const int N,
               const float* __restrict__ W, float* __restrict__ pp)
{
    __shared__ float sA[BK][BM + 4];
    __shared__ float sB[BK][BN + 4];

    const int tid = threadIdx.x;
    const int tx  = tid & 15;
    const int ty  = tid >> 4;
    const int n0  = blockIdx.x * BN;
    const int m0  = blockIdx.y * BM;
    const int kbase = blockIdx.z * 512;

    const int lr  = tid >> 2;          // staged row
    const int klc = (tid & 3) << 4;    // 16 consecutive k per thread

    float S[4][4];
    #pragma unroll
    for (int i = 0; i < 4; ++i)
        #pragma unroll
        for (int j = 0; j < 4; ++j) S[i][j] = 0.0f;

    const float* aF = (const float*)Ain + (size_t)(m0 + lr) * K + kbase + klc;
    const u64*   aM = (const u64*)Ain   + (size_t)(m0 + lr) * K + kbase + klc;
    const float* wp = W + (size_t)(n0 + lr) * K + kbase + klc;

    float4 fa[4]; uint4 ma[8]; float4 fw[4];

    auto loadA = [&](int k0) {
        if constexpr (IN_MASK) {
            const uint4* p = reinterpret_cast<const uint4*>(aM + k0);
            #pragma unroll
            for (int c = 0; c < 8; ++c) ma[c] = p[c];
        } else {
            #pragma unroll
            for (int c = 0; c < 4; ++c)
                fa[c] = *reinterpret_cast<const float4*>(aF + k0 + 4 * c);
        }
    };
    auto loadW = [&](int k0) {
        #pragma unroll
        for (int c = 0; c < 4; ++c)
            fw[c] = *reinterpret_cast<const float4*>(wp + k0 + 4 * c);
    };

    constexpr int NT = 512 / BK;   // 8 tiles per chain
    loadA(0); loadW(0);

    for (int t = 0; t < NT; ++t) {
        __syncthreads();
        if constexpr (IN_MASK) {
            #pragma unroll
            for (int i = 0; i < 16; ++i) {
                const u32 lo = (i & 1) ? ma[i >> 1].z : ma[i >> 1].x;
                const u32 hi = (i & 1) ? ma[i >> 1].w : ma[i >> 1].y;
                sA[klc + i][lr] = __fdiv_rn((float)(__popc(lo) + __popc(hi)), 50.0f);
            }
        } else {
            #pragma unroll
            for (int c = 0; c < 4; ++c) {
                sA[klc + 4 * c + 0][lr] = fa[c].x;
                sA[klc + 4 * c + 1][lr] = fa[c].y;
                sA[klc + 4 * c + 2][lr] = fa[c].z;
                sA[klc + 4 * c + 3][lr] = fa[c].w;
            }
        }
        #pragma unroll
        for (int c = 0; c < 4; ++c) {
            sB[klc + 4 * c + 0][lr] = fw[c].x;
            sB[klc + 4 * c + 1][lr] = fw[c].y;
            sB[klc + 4 * c + 2][lr] = fw[c].z;
            sB[klc + 4 * c + 3][lr] = fw[c].w;
        }
        __syncthreads();

        if (t + 1 < NT) { loadA((t + 1) * BK); loadW((t + 1) * BK); }

        #pragma unroll
        for (int kk = 0; kk < BK; ++kk) {
            const float4 a4 = *reinterpret_cast<const float4*>(&sA[kk][ty * 4]);
            const float4 b4 = *reinterpret_cast<const float4*>(&sB[kk][tx * 4]);
            const float a[4] = {a4.x, a4.y, a4.z, a4.w};
            const float b[4] = {b4.x, b4.y, b4.z, b4.w};
            #pragma unroll
            for (int i = 0; i < 4; ++i)
                #pragma unroll
                for (int j = 0; j < 4; ++j)
                    S[i][j] = __fmaf_rn(a[i], b[j], S[i][j]);
        }
    }

    float* dst = pp + (size_t)blockIdx.z * M * N;
    #pragma unroll
    for (int i = 0; i < 4; ++i)
        #pragma unroll
        for (int j = 0; j < 4; ++j)
            dst[(size_t)(m0 + ty * 4 + i) * N + (n0 + tx * 4 + j)] = S[i][j];
}

// ---------------------------------------------------------------------------
// Merge chains (ordered fadd: ((p0+p1)+p2)+p3), + bias, LIF -> mask,
// then expand spikes (block = 256 consecutive neurons, streaming writes).
// ---------------------------------------------------------------------------
template<bool DUP, bool WMASK>
__global__ __launch_bounds__(TPB)
void merge_lif_expand(const float* __restrict__ pp, const int nchain,
                      const int N, const float* __restrict__ bias,
                      u64* __restrict__ maskOut, float* __restrict__ out,
                      float* __restrict__ dup)
{
    __shared__ u64 lm[TPB];
    const int tid = threadIdx.x;
    const size_t base = (size_t)blockIdx.x * TPB;
    const size_t idx  = base + tid;
    const size_t cs   = (size_t)M * N;

    float s = pp[idx];
    for (int c = 1; c < nchain; ++c) s = __fadd_rn(s, pp[(size_t)c * cs + idx]);
    const float I = __fadd_rn(s, bias[idx & (size_t)(N - 1)]);

    float V = 0.0f; u64 msk = 0ull;
    #pragma unroll 1
    for (int t = 0; t < T; ++t) {
        V = __fadd_rn(__fmul_rn(V, 0.9f), I);
        if (V > 1.0f) { V = 0.0f; msk |= (1ull << t); }
    }
    if constexpr (WMASK) maskOut[idx] = msk;
    lm[tid] = msk;
    __syncthreads();

    constexpr int TOTQ = TPB * T / 4;   // 3200 float4s
    for (int q4 = tid; q4 < TOTQ; q4 += TPB) {
        const int q = q4 << 2;
        int nn = q / T;
        int tt = q - nn * T;
        u64 mk = lm[nn];
        float vals[4];
        #pragma unroll
        for (int c = 0; c < 4; ++c) {
            if (tt >= T) { tt -= T; ++nn; mk = lm[nn]; }
            vals[c] = (float)((mk >> tt) & 1ull);
            ++tt;
        }
        const float4 v4 = make_float4(vals[0], vals[1], vals[2], vals[3]);
        const size_t off = base * T + q;
        *reinterpret_cast<float4*>(out + off) = v4;
        if constexpr (DUP) *reinterpret_cast<float4*>(dup + off) = v4;
    }
}

// ---------------------------------------------------------------------------
// Fallback (r19-proven): fused GEMM+LIF->mask kernel, expand kernel, copy.
// ---------------------------------------------------------------------------
template<bool IN_MASK>
__global__ __launch_bounds__(TPB)
void lif_gemm_mask(const void* __restrict__ Ain, const int K, const int N,
                   const float* __restrict__ W, const float* __restrict__ bias,
                   u64* __restrict__ maskOut)
{
    __shared__ float sA[BK][BM + 4];
    __shared__ float sB[BK][BN + 4];
    const int tid = threadIdx.x;
    const int tx = tid & 15, ty = tid >> 4;
    const int n0 = blockIdx.x * BN, m0 = blockIdx.y * BM;
    const int lr = tid >> 2, klc = (tid & 3) << 4;

    float S[4][4], Ia[4][4];
    #pragma unroll
    for (int i = 0; i < 4; ++i)
        #pragma unroll
        for (int j = 0; j < 4; ++j) { S[i][j] = 0.0f; Ia[i][j] = 0.0f; }

    const float* aF = (const float*)Ain + (size_t)(m0 + lr) * K + klc;
    const u64*   aM = (const u64*)Ain   + (size_t)(m0 + lr) * K + klc;
    const float* wp = W + (size_t)(n0 + lr) * K + klc;
    float4 fa[4]; uint4 ma[8]; float4 fw[4];

    auto loadA = [&](int k0) {
        if constexpr (IN_MASK) {
            const uint4* p = reinterpret_cast<const uint4*>(aM + k0);
            #pragma unroll
            for (int c = 0; c < 8; ++c) ma[c] = p[c];
        } else {
            #pragma unroll
            for (int c = 0; c < 4; ++c)
                fa[c] = *reinterpret_cast<const float4*>(aF + k0 + 4 * c);
        }
    };
    auto loadW = [&](int k0) {
        #pragma unroll
        for (int c = 0; c < 4; ++c)
            fw[c] = *reinterpret_cast<const float4*>(wp + k0 + 4 * c);
    };

    const int NT = K / BK;
    loadA(0); loadW(0);
    for (int t = 0; t < NT; ++t) {
        __syncthreads();
        if constexpr (IN_MASK) {
            #pragma unroll
            for (int i = 0; i < 16; ++i) {
                const u32 lo = (i & 1) ? ma[i >> 1].z : ma[i >> 1].x;
                const u32 hi = (i & 1) ? ma[i >> 1].w : ma[i >> 1].y;
                sA[klc + i][lr] = __fdiv_rn((float)(__popc(lo) + __popc(hi)), 50.0f);
            }
        } else {
            #pragma unroll
            for (int c = 0; c < 4; ++c) {
                sA[klc + 4 * c + 0][lr] = fa[c].x;
                sA[klc + 4 * c + 1][lr] = fa[c].y;
                sA[klc + 4 * c + 2][lr] = fa[c].z;
                sA[klc + 4 * c + 3][lr] = fa[c].w;
            }
        }
        #pragma unroll
        for (int c = 0; c < 4; ++c) {
            sB[klc + 4 * c + 0][lr] = fw[c].x;
            sB[klc + 4 * c + 1][lr] = fw[c].y;
            sB[klc + 4 * c + 2][lr] = fw[c].z;
            sB[klc + 4 * c + 3][lr] = fw[c].w;
        }
        __syncthreads();
        if (t + 1 < NT) { loadA((t + 1) * BK); loadW((t + 1) * BK); }
        #pragma unroll
        for (int kk = 0; kk < BK; ++kk) {
            const float4 a4 = *reinterpret_cast<const float4*>(&sA[kk][ty * 4]);
            const float4 b4 = *reinterpret_cast<const float4*>(&sB[kk][tx * 4]);
            const float a[4] = {a4.x, a4.y, a4.z, a4.w};
            const float b[4] = {b4.x, b4.y, b4.z, b4.w};
            #pragma unroll
            for (int i = 0; i < 4; ++i)
                #pragma unroll
                for (int j = 0; j < 4; ++j)
                    S[i][j] = __fmaf_rn(a[i], b[j], S[i][j]);
        }
        if ((((t + 1) * BK) & 511) == 0) {
            #pragma unroll
            for (int i = 0; i < 4; ++i)
                #pragma unroll
                for (int j = 0; j < 4; ++j) {
                    Ia[i][j] = __fadd_rn(Ia[i][j], S[i][j]);
                    S[i][j]  = 0.0f;
                }
        }
    }
    #pragma unroll
    for (int i = 0; i < 4; ++i)
        #pragma unroll
        for (int j = 0; j < 4; ++j) {
            const int mi = ty * 4 + i, nj = tx * 4 + j;
            const float I = __fadd_rn(Ia[i][j], bias[n0 + nj]);
            float V = 0.0f; u64 msk = 0ull;
            #pragma unroll 1
            for (int t = 0; t < T; ++t) {
                V = __fadd_rn(__fmul_rn(V, 0.9f), I);
                if (V > 1.0f) { V = 0.0f; msk |= (1ull << t); }
            }
            maskOut[(size_t)(m0 + mi) * N + (n0 + nj)] = msk;
        }
}

template<bool DUP>
__global__ __launch_bounds__(TPB)
void expand_spikes(const u64* __restrict__ mask, float* __restrict__ out,
                   float* __restrict__ dup)
{
    __shared__ u64 lm[TPB];
    const int tid = threadIdx.x;
    const size_t base = (size_t)blockIdx.x * TPB;
    lm[tid] = mask[base + tid];
    __syncthreads();
    constexpr int TOTQ = TPB * T / 4;
    for (int q4 = tid; q4 < TOTQ; q4 += TPB) {
        const int q = q4 << 2;
        int nn = q / T, tt = q - nn * T;
        u64 mk = lm[nn];
        float vals[4];
        #pragma unroll
        for (int c = 0; c < 4; ++c) {
            if (tt >= T) { tt -= T; ++nn; mk = lm[nn]; }
            vals[c] = (float)((mk >> tt) & 1ull);
            ++tt;
        }
        const float4 v4 = make_float4(vals[0], vals[1], vals[2], vals[3]);
        const size_t off = base * T + q;
        *reinterpret_cast<float4*>(out + off) = v4;
        if constexpr (DUP) *reinterpret_cast<float4*>(dup + off) = v4;
    }
}

__global__ __launch_bounds__(TPB)
void copy_f4(const float* __restrict__ src, float* __restrict__ dst, int nquads)
{
    int i = blockIdx.x * blockDim.x + threadIdx.x;
    int stride = gridDim.x * blockDim.x;
    for (; i < nquads; i += stride)
        reinterpret_cast<float4*>(dst)[i] = reinterpret_cast<const float4*>(src)[i];
}

extern "C" void kernel_launch(void* const* d_in, const int* in_sizes, int n_in,
                              void* d_out, int out_size, void* d_ws, size_t ws_size,
                              hipStream_t stream) {
    const float* x  = (const float*)d_in[0];
    const float* W0 = (const float*)d_in[1];
    const float* b0 = (const float*)d_in[2];
    const float* W1 = (const float*)d_in[3];
    const float* b1 = (const float*)d_in[4];
    const float* W2 = (const float*)d_in[5];
    const float* b2 = (const float*)d_in[6];
    float* out = (float*)d_out;

    constexpr int H = 2048, DOUT = 1024;
    const size_t s2sz = (size_t)M * DOUT * T;
    const size_t s0sz = (size_t)M * H * T;
    const size_t NH = (size_t)M * H;       // 1,048,576
    const size_t ND = (size_t)M * DOUT;    // 524,288

    // d_out layout (f32, r13/r17-proven): [s2a | s0 | s1 | s2b]
    float* s2a = out;
    float* s0  = out + s2sz;
    float* s1  = s0 + s0sz;
    float* s2b = s1 + s0sz;

    dim3 blk(TPB);
    const size_t WS_NEED = (2 * NH + 4 * NH + 4 * ND) * sizeof(float)
                         + (NH + NH) * sizeof(u64);   // 48 MB

    if (ws_size >= WS_NEED) {
        float* pp0 = (float*)d_ws;            // 2 chains x NH
        float* pp1 = pp0 + 2 * NH;            // 4 chains x NH
        float* pp2 = pp1 + 4 * NH;            // 4 chains x ND
        u64* mask0 = (u64*)(pp2 + 4 * ND);
        u64* mask1 = mask0 + NH;

        gemm_part<false><<<dim3(H / BN, M / BM, 2), blk, 0, stream>>>(
            x, 1024, H, W0, pp0);
        merge_lif_expand<false, true><<<(int)(NH / TPB), blk, 0, stream>>>(
            pp0, 2, H, b0, mask0, s0, nullptr);
        gemm_part<true><<<dim3(H / BN, M / BM, 4), blk, 0, stream>>>(
            mask0, H, H, W1, pp1);
        merge_lif_expand<false, true><<<(int)(NH / TPB), blk, 0, stream>>>(
            pp1, 4, H, b1, mask1, s1, nullptr);
        gemm_part<true><<<dim3(DOUT / BN, M / BM, 4), blk, 0, stream>>>(
            mask1, H, DOUT, W2, pp2);
        merge_lif_expand<true, false><<<(int)(ND / TPB), blk, 0, stream>>>(
            pp2, 4, DOUT, b2, nullptr, s2b, s2a);
    } else if (ws_size >= ND * sizeof(u64)) {
        // r19 fast fallback: masks in d_out stashes + d_ws
        u64* mask0 = (u64*)s1;
        u64* mask1 = (u64*)s2a;
        u64* mask2 = (u64*)d_ws;
        dim3 gH(H / BN, M / BM), gD(DOUT / BN, M / BM);
        lif_gemm_mask<false><<<gH, blk, 0, stream>>>(x, 1024, H, W0, b0, mask0);
        lif_gemm_mask<true ><<<gH, blk, 0, stream>>>(mask0, H, H, W1, b1, mask1);
        lif_gemm_mask<true ><<<gD, blk, 0, stream>>>(mask1, H, DOUT, W2, b2, mask2);
        expand_spikes<false><<<(int)(NH / TPB), blk, 0, stream>>>(mask0, s0, nullptr);
        expand_spikes<false><<<(int)(NH / TPB), blk, 0, stream>>>(mask1, s1, nullptr);
        expand_spikes<true ><<<(int)(ND / TPB), blk, 0, stream>>>(mask2, s2b, s2a);
    } else {
        // minimal-ws fallback
        u64* mask0 = (u64*)s1;
        u64* mask1 = (u64*)s2a;
        dim3 gH(H / BN, M / BM), gD(DOUT / BN, M / BM);
        lif_gemm_mask<false><<<gH, blk, 0, stream>>>(x, 1024, H, W0, b0, mask0);
        lif_gemm_mask<true ><<<gH, blk, 0, stream>>>(mask0, H, H, W1, b1, mask1);
        expand_spikes<false><<<(int)(NH / TPB), blk, 0, stream>>>(mask0, s0, nullptr);
        u64* mask2 = (u64*)s0;   // s0 fully written; head reused after B0
        lif_gemm_mask<true ><<<gD, blk, 0, stream>>>(mask1, H, DOUT, W2, b2, mask2);
        expand_spikes<false><<<(int)(NH / TPB), blk, 0, stream>>>(mask1, s1, nullptr);
        expand_spikes<true ><<<(int)(ND / TPB), blk, 0, stream>>>(mask2, s2b, s2a);
        // restore s0 head overwritten by mask2 stash: re-expand from mask0?
        // mask0 (s1 head) was killed by s1 expand -> instead re-derive:
        // NOTE: this branch is defensive only; re-expand s0 head from masks
        // is impossible here, so recompute layer0 for the head region:
        lif_gemm_mask<false><<<dim3(H / BN, 1), blk, 0, stream>>>(x, 1024, H, W0, b0, (u64*)s2b);
        // (s2b head temporarily reused then rewritten below)
        expand_spikes<false><<<(int)(NH / TPB / 8), blk, 0, stream>>>((u64*)s2b, s0, nullptr);
        lif_gemm_mask<true ><<<gD, blk, 0, stream>>>(mask1, H, DOUT, W2, b2, (u64*)s2a);
        expand_spikes<true ><<<(int)(ND / TPB), blk, 0, stream>>>((u64*)s2a, s2b, s2a);
    }
}

// Round 21
// 267.115 us; speedup vs baseline: 2.5733x; 1.1171x over previous
//
#include <hip/hip_runtime.h>

typedef unsigned long long u64;
typedef unsigned int u32;

constexpr int TPB = 256;
constexpr int T  = 50;
constexpr int M  = 512;   // batch

// ---------------------------------------------------------------------------
// A-kernel (split-K, wide tile): ONE KC=512 chain partial of C = A @ W^T.
// Block tile 128x64, per-thread 8x4, 256 threads. blockIdx.z = chain.
// Per-element order: single sequential k-ascending FMA chain (r16-certified).
// A is always float (means precomputed by the merge kernel).
// ---------------------------------------------------------------------------
__global__ __launch_bounds__(TPB)
void gemm_part(const float* __restrict__ A, const int K, const int N,
               const float* __restrict__ W, float* __restrict__ pp)
{
    constexpr int BM2 = 128, BN2 = 64, BK = 64;
    __shared__ float sA[BK][BM2 + 4];
    __shared__ float sB[BK][BN2 + 4];

    const int tid = threadIdx.x;
    const int tx  = tid & 15;        // 16 col groups x 4
    const int ty  = tid >> 4;        // 16 row groups x 8
    const int n0  = blockIdx.x * BN2;
    const int m0  = blockIdx.y * BM2;
    const int kbase = blockIdx.z * 512;

    // staging maps: A row = tid>>1 (128 rows), k-seg = (tid&1)*32
    //               W row = tid>>2 (64 rows),  k-seg = (tid&3)*16
    const int ar = tid >> 1, aks = (tid & 1) << 5;
    const int wr = tid >> 2, wks = (tid & 3) << 4;

    float S[8][4];
    #pragma unroll
    for (int i = 0; i < 8; ++i)
        #pragma unroll
        for (int j = 0; j < 4; ++j) S[i][j] = 0.0f;

    const float* aP = A + (size_t)(m0 + ar) * K + kbase + aks;
    const float* wP = W + (size_t)(n0 + wr) * K + kbase + wks;

    float4 fa[8], fw[4];
    auto loadA = [&](int t) {
        #pragma unroll
        for (int c = 0; c < 8; ++c)
            fa[c] = *reinterpret_cast<const float4*>(aP + t * BK + 4 * c);
    };
    auto loadW = [&](int t) {
        #pragma unroll
        for (int c = 0; c < 4; ++c)
            fw[c] = *reinterpret_cast<const float4*>(wP + t * BK + 4 * c);
    };

    constexpr int NT = 512 / BK;   // 8 tiles per chain
    loadA(0); loadW(0);

    for (int t = 0; t < NT; ++t) {
        __syncthreads();
        #pragma unroll
        for (int c = 0; c < 8; ++c) {
            sA[aks + 4 * c + 0][ar] = fa[c].x;
            sA[aks + 4 * c + 1][ar] = fa[c].y;
            sA[aks + 4 * c + 2][ar] = fa[c].z;
            sA[aks + 4 * c + 3][ar] = fa[c].w;
        }
        #pragma unroll
        for (int c = 0; c < 4; ++c) {
            sB[wks + 4 * c + 0][wr] = fw[c].x;
            sB[wks + 4 * c + 1][wr] = fw[c].y;
            sB[wks + 4 * c + 2][wr] = fw[c].z;
            sB[wks + 4 * c + 3][wr] = fw[c].w;
        }
        __syncthreads();

        if (t + 1 < NT) { loadA(t + 1); loadW(t + 1); }

        #pragma unroll
        for (int kk = 0; kk < BK; ++kk) {
            const float4 a0 = *reinterpret_cast<const float4*>(&sA[kk][ty * 8]);
            const float4 a1 = *reinterpret_cast<const float4*>(&sA[kk][ty * 8 + 4]);
            const float4 b4 = *reinterpret_cast<const float4*>(&sB[kk][tx * 4]);
            const float a[8] = {a0.x, a0.y, a0.z, a0.w, a1.x, a1.y, a1.z, a1.w};
            const float b[4] = {b4.x, b4.y, b4.z, b4.w};
            #pragma unroll
            for (int i = 0; i < 8; ++i)
                #pragma unroll
                for (int j = 0; j < 4; ++j)
                    S[i][j] = __fmaf_rn(a[i], b[j], S[i][j]);
        }
    }

    float* dst = pp + (size_t)blockIdx.z * M * N;
    #pragma unroll
    for (int i = 0; i < 8; ++i) {
        const size_t off = (size_t)(m0 + ty * 8 + i) * N + (n0 + tx * 4);
        *reinterpret_cast<float4*>(dst + off) =
            make_float4(S[i][0], S[i][1], S[i][2], S[i][3]);
    }
}

// ---------------------------------------------------------------------------
// Merge chains (ordered fadd), + bias, LIF, emit mean floats (optional),
// then expand spikes (block = 256 consecutive neurons, streaming writes).
// ---------------------------------------------------------------------------
template<bool DUP, bool WMEAN>
__global__ __launch_bounds__(TPB)
void merge_lif_expand(const float* __restrict__ pp, const int nchain,
                      const int N, const float* __restrict__ bias,
                      float* __restrict__ meanOut, float* __restrict__ out,
                      float* __restrict__ dup)
{
    __shared__ u64 lm[TPB];
    const int tid = threadIdx.x;
    const size_t base = (size_t)blockIdx.x * TPB;
    const size_t idx  = base + tid;
    const size_t cs   = (size_t)M * N;

    float s = pp[idx];
    for (int c = 1; c < nchain; ++c) s = __fadd_rn(s, pp[(size_t)c * cs + idx]);
    const float I = __fadd_rn(s, bias[idx & (size_t)(N - 1)]);

    float V = 0.0f; u64 msk = 0ull;
    #pragma unroll 1
    for (int t = 0; t < T; ++t) {
        V = __fadd_rn(__fmul_rn(V, 0.9f), I);
        if (V > 1.0f) { V = 0.0f; msk |= (1ull << t); }
    }
    if constexpr (WMEAN)
        meanOut[idx] = __fdiv_rn((float)__popcll(msk), 50.0f);
    lm[tid] = msk;
    __syncthreads();

    constexpr int TOTQ = TPB * T / 4;   // 3200 float4s
    for (int q4 = tid; q4 < TOTQ; q4 += TPB) {
        const int q = q4 << 2;
        int nn = q / T;
        int tt = q - nn * T;
        u64 mk = lm[nn];
        float vals[4];
        #pragma unroll
        for (int c = 0; c < 4; ++c) {
            if (tt >= T) { tt -= T; ++nn; mk = lm[nn]; }
            vals[c] = (float)((mk >> tt) & 1ull);
            ++tt;
        }
        const float4 v4 = make_float4(vals[0], vals[1], vals[2], vals[3]);
        const size_t off = base * T + q;
        *reinterpret_cast<float4*>(out + off) = v4;
        if constexpr (DUP) *reinterpret_cast<float4*>(dup + off) = v4;
    }
}

// ---------------------------------------------------------------------------
// Fallback (r19-proven): fused GEMM+LIF->mask kernel + expand kernels.
// ---------------------------------------------------------------------------
template<bool IN_MASK>
__global__ __launch_bounds__(TPB)
void lif_gemm_mask(const void* __restrict__ Ain, const int K, const int N,
                   const float* __restrict__ W, const float* __restrict__ bias,
                   u64* __restrict__ maskOut)
{
    constexpr int BM = 64, BN = 64, BK = 64;
    __shared__ float sA[BK][BM + 4];
    __shared__ float sB[BK][BN + 4];
    const int tid = threadIdx.x;
    const int tx = tid & 15, ty = tid >> 4;
    const int n0 = blockIdx.x * BN, m0 = blockIdx.y * BM;
    const int lr = tid >> 2, klc = (tid & 3) << 4;

    float S[4][4], Ia[4][4];
    #pragma unroll
    for (int i = 0; i < 4; ++i)
        #pragma unroll
        for (int j = 0; j < 4; ++j) { S[i][j] = 0.0f; Ia[i][j] = 0.0f; }

    const float* aF = (const float*)Ain + (size_t)(m0 + lr) * K + klc;
    const u64*   aM = (const u64*)Ain   + (size_t)(m0 + lr) * K + klc;
    const float* wp = W + (size_t)(n0 + lr) * K + klc;
    float4 fa[4]; uint4 ma[8]; float4 fw[4];

    auto loadA = [&](int k0) {
        if constexpr (IN_MASK) {
            const uint4* p = reinterpret_cast<const uint4*>(aM + k0);
            #pragma unroll
            for (int c = 0; c < 8; ++c) ma[c] = p[c];
        } else {
            #pragma unroll
            for (int c = 0; c < 4; ++c)
                fa[c] = *reinterpret_cast<const float4*>(aF + k0 + 4 * c);
        }
    };
    auto loadW = [&](int k0) {
        #pragma unroll
        for (int c = 0; c < 4; ++c)
            fw[c] = *reinterpret_cast<const float4*>(wp + k0 + 4 * c);
    };

    const int NT = K / BK;
    loadA(0); loadW(0);
    for (int t = 0; t < NT; ++t) {
        __syncthreads();
        if constexpr (IN_MASK) {
            #pragma unroll
            for (int i = 0; i < 16; ++i) {
                const u32 lo = (i & 1) ? ma[i >> 1].z : ma[i >> 1].x;
                const u32 hi = (i & 1) ? ma[i >> 1].w : ma[i >> 1].y;
                sA[klc + i][lr] = __fdiv_rn((float)(__popc(lo) + __popc(hi)), 50.0f);
            }
        } else {
            #pragma unroll
            for (int c = 0; c < 4; ++c) {
                sA[klc + 4 * c + 0][lr] = fa[c].x;
                sA[klc + 4 * c + 1][lr] = fa[c].y;
                sA[klc + 4 * c + 2][lr] = fa[c].z;
                sA[klc + 4 * c + 3][lr] = fa[c].w;
            }
        }
        #pragma unroll
        for (int c = 0; c < 4; ++c) {
            sB[klc + 4 * c + 0][lr] = fw[c].x;
            sB[klc + 4 * c + 1][lr] = fw[c].y;
            sB[klc + 4 * c + 2][lr] = fw[c].z;
            sB[klc + 4 * c + 3][lr] = fw[c].w;
        }
        __syncthreads();
        if (t + 1 < NT) { loadA((t + 1) * BK); loadW((t + 1) * BK); }
        #pragma unroll
        for (int kk = 0; kk < BK; ++kk) {
            const float4 a4 = *reinterpret_cast<const float4*>(&sA[kk][ty * 4]);
            const float4 b4 = *reinterpret_cast<const float4*>(&sB[kk][tx * 4]);
            const float a[4] = {a4.x, a4.y, a4.z, a4.w};
            const float b[4] = {b4.x, b4.y, b4.z, b4.w};
            #pragma unroll
            for (int i = 0; i < 4; ++i)
                #pragma unroll
                for (int j = 0; j < 4; ++j)
                    S[i][j] = __fmaf_rn(a[i], b[j], S[i][j]);
        }
        if ((((t + 1) * BK) & 511) == 0) {
            #pragma unroll
            for (int i = 0; i < 4; ++i)
                #pragma unroll
                for (int j = 0; j < 4; ++j) {
                    Ia[i][j] = __fadd_rn(Ia[i][j], S[i][j]);
                    S[i][j]  = 0.0f;
                }
        }
    }
    #pragma unroll
    for (int i = 0; i < 4; ++i)
        #pragma unroll
        for (int j = 0; j < 4; ++j) {
            const int mi = ty * 4 + i, nj = tx * 4 + j;
            const float I = __fadd_rn(Ia[i][j], bias[n0 + nj]);
            float V = 0.0f; u64 msk = 0ull;
            #pragma unroll 1
            for (int t = 0; t < T; ++t) {
                V = __fadd_rn(__fmul_rn(V, 0.9f), I);
                if (V > 1.0f) { V = 0.0f; msk |= (1ull << t); }
            }
            maskOut[(size_t)(m0 + mi) * N + (n0 + nj)] = msk;
        }
}

template<bool DUP>
__global__ __launch_bounds__(TPB)
void expand_spikes(const u64* __restrict__ mask, float* __restrict__ out,
                   float* __restrict__ dup)
{
    __shared__ u64 lm[TPB];
    const int tid = threadIdx.x;
    const size_t base = (size_t)blockIdx.x * TPB;
    lm[tid] = mask[base + tid];
    __syncthreads();
    constexpr int TOTQ = TPB * T / 4;
    for (int q4 = tid; q4 < TOTQ; q4 += TPB) {
        const int q = q4 << 2;
        int nn = q / T, tt = q - nn * T;
        u64 mk = lm[nn];
        float vals[4];
        #pragma unroll
        for (int c = 0; c < 4; ++c) {
            if (tt >= T) { tt -= T; ++nn; mk = lm[nn]; }
            vals[c] = (float)((mk >> tt) & 1ull);
            ++tt;
        }
        const float4 v4 = make_float4(vals[0], vals[1], vals[2], vals[3]);
        const size_t off = base * T + q;
        *reinterpret_cast<float4*>(out + off) = v4;
        if constexpr (DUP) *reinterpret_cast<float4*>(dup + off) = v4;
    }
}

extern "C" void kernel_launch(void* const* d_in, const int* in_sizes, int n_in,
                              void* d_out, int out_size, void* d_ws, size_t ws_size,
                              hipStream_t stream) {
    const float* x  = (const float*)d_in[0];
    const float* W0 = (const float*)d_in[1];
    const float* b0 = (const float*)d_in[2];
    const float* W1 = (const float*)d_in[3];
    const float* b1 = (const float*)d_in[4];
    const float* W2 = (const float*)d_in[5];
    const float* b2 = (const float*)d_in[6];
    float* out = (float*)d_out;

    constexpr int H = 2048, DOUT = 1024;
    const size_t s2sz = (size_t)M * DOUT * T;
    const size_t s0sz = (size_t)M * H * T;
    const size_t NH = (size_t)M * H;       // 1,048,576
    const size_t ND = (size_t)M * DOUT;    // 524,288

    // d_out layout (f32, r13/r17-proven): [s2a | s0 | s1 | s2b]
    float* s2a = out;
    float* s0  = out + s2sz;
    float* s1  = s0 + s0sz;
    float* s2b = s1 + s0sz;

    dim3 blk(TPB);
    const size_t WS_NEED = (2 * NH + 4 * NH + 4 * ND + 2 * NH) * sizeof(float);

    if (ws_size >= WS_NEED) {
        float* pp0   = (float*)d_ws;          // 2 chains x NH
        float* pp1   = pp0 + 2 * NH;          // 4 chains x NH
        float* pp2   = pp1 + 4 * NH;          // 4 chains x ND
        float* mean0 = pp2 + 4 * ND;          // NH floats
        float* mean1 = mean0 + NH;            // NH floats

        gemm_part<<<dim3(H / 64, M / 128, 2), blk, 0, stream>>>(
            x, 1024, H, W0, pp0);
        merge_lif_expand<false, true><<<(int)(NH / TPB), blk, 0, stream>>>(
            pp0, 2, H, b0, mean0, s0, nullptr);
        gemm_part<<<dim3(H / 64, M / 128, 4), blk, 0, stream>>>(
            mean0, H, H, W1, pp1);
        merge_lif_expand<false, true><<<(int)(NH / TPB), blk, 0, stream>>>(
            pp1, 4, H, b1, mean1, s1, nullptr);
        gemm_part<<<dim3(DOUT / 64, M / 128, 4), blk, 0, stream>>>(
            mean1, H, DOUT, W2, pp2);
        merge_lif_expand<true, false><<<(int)(ND / TPB), blk, 0, stream>>>(
            pp2, 4, DOUT, b2, nullptr, s2b, s2a);
    } else {
        // r19-proven fallback: masks in d_out stashes + d_ws
        u64* mask0 = (u64*)s1;
        u64* mask1 = (u64*)s2a;
        u64* mask2 = (u64*)d_ws;
        dim3 gH(H / 64, M / 64), gD(DOUT / 64, M / 64);
        lif_gemm_mask<false><<<gH, blk, 0, stream>>>(x, 1024, H, W0, b0, mask0);
        lif_gemm_mask<true ><<<gH, blk, 0, stream>>>(mask0, H, H, W1, b1, mask1);
        lif_gemm_mask<true ><<<gD, blk, 0, stream>>>(mask1, H, DOUT, W2, b2, mask2);
        expand_spikes<false><<<(int)(NH / TPB), blk, 0, stream>>>(mask0, s0, nullptr);
        expand_spikes<false><<<(int)(NH / TPB), blk, 0, stream>>>(mask1, s1, nullptr);
        expand_spikes<true ><<<(int)(ND / TPB), blk, 0, stream>>>(mask2, s2b, s2a);
    }
}